// Round 18
// baseline (90.036 us; speedup 1.0000x reference)
//
#include <hip/hip_runtime.h>
#include <hip/hip_fp16.h>

// Adaptive downsampler: B=8, C=3, 1024x1024 -> 512x512, K2=9 taps,
// bilinear gather from reflect-padded (pad=1) image, weighted by kernels.
// R18 = R17 (66.0us: fdot2 bilinear on fp16 packed-pair LDS 25x136x3
//       window/40960B, 512-thr/64x8 patch, 27-wide nt preload, XCD slab
//       swizzle, exact fp32 fallback, plain stores)
//       + setup-before-barrier: per-tap setup (px/py, floor, window test,
//       packed weight folding) depends only on stream values, so it runs
//       DURING the staging phase (fills global-load latency bubbles).
//       Phase B after the barrier = 27x {ds_read2 + 2 fdot2} + cold
//       fallback (reloads its 3 stream values from global; exact).
constexpr int B_  = 8;
constexpr int C_  = 3;
constexpr int H_  = 1024;
constexpr int W_  = 1024;
constexpr int HO_ = 512;
constexpr int WO_ = 512;
constexpr int K2_ = 9;
constexpr int KS_ = 3;
constexpr int HP_ = H_ + 2;   // padded height (pad=1)
constexpr int WP_ = W_ + 2;   // padded width
constexpr int TPB_  = 512;
constexpr int NBLK_ = (B_ * HO_ * WO_) / TPB_;  // 4096 blocks
constexpr int NXCD_ = 8;

// LDS window: WY_ rows x WX_ pair-cols x 3 channels (half2 per entry)
constexpr int WY_  = 25;
constexpr int WX_  = 136;
constexpr int WX4_ = WX_ / 4;              // 34 staging units per row
constexpr int WCH_ = WY_ * WX_;            // 3400 entries per channel
constexpr int NF4_ = 3 * WY_ * WX4_;       // 2550 staging units

typedef __fp16 h2v __attribute__((ext_vector_type(2)));

__device__ __forceinline__ float2 ld2(const float* p) {
    float2 r;
    __builtin_memcpy(&r, p, sizeof(float2));   // global_load_dwordx2
    return r;
}

__device__ __forceinline__ h2v ldh2(const __half2* p) {
    h2v r;
    __builtin_memcpy(&r, p, sizeof(h2v));      // ds_read_b32 (read2-paired)
    return r;
}

__global__ __launch_bounds__(TPB_) void ds_kernel(
    const float* __restrict__ img,
    const float* __restrict__ kern,
    const float* __restrict__ offh,
    const float* __restrict__ offv,
    const float* __restrict__ unit_p,
    float* __restrict__ out)
{
    const int HWo = HO_ * WO_;                       // 262144
    __shared__ __half2 shp[3 * WCH_];                // 40800 B -> 40960 alloc

    // XCD swizzle: block i runs on XCD i%8; contiguous 512-block slab
    // per XCD = one batch, oy-ordered -> image window L2-resident.
    const int wg  = blockIdx.x;
    const int nid = (wg & (NXCD_ - 1)) * (NBLK_ / NXCD_) + (wg >> 3);

    // 2D patch decode: nid = b*512 + oyt*8 + oxt
    const int b   = nid >> 9;
    const int q   = nid & 511;
    const int oyt = q >> 3;             // 0..63: 8-row oy group
    const int oxt = q & 7;              // 0..7:  64-px ox chunk
    const int wv  = threadIdx.x >> 6;   // 0..7
    const int ln  = threadIdx.x & 63;
    const int oy  = oyt * 8 + wv;
    const int ox  = oxt * 64 + ln;

    const float unit = unit_p[0];
    const float* imgb = img + (size_t)b * (C_ * H_ * W_);
    const int kbase = b * (K2_ * HWo) + oy * WO_ + ox;   // < 2^25

    // Window origin (orig-image coords), x 4-aligned for float4 staging.
    int wxlo = 128 * oxt - 4;
    wxlo = wxlo < 0 ? 0 : (wxlo > W_ - WX_ ? W_ - WX_ : wxlo);   // 0..888, %4==0
    int wylo = 16 * oyt - 4;
    wylo = wylo < 0 ? 0 : (wylo > H_ - WY_ ? H_ - WY_ : wylo);   // 0..999

    // Phase 1: all 27 stream loads in flight (read-once -> nontemporal).
    float wk[K2_], oh[K2_], ov[K2_];
#pragma unroll
    for (int k = 0; k < K2_; ++k) {
        wk[k] = __builtin_nontemporal_load(kern + kbase + k * HWo);
        oh[k] = __builtin_nontemporal_load(offh + kbase + k * HWo);
        ov[k] = __builtin_nontemporal_load(offv + kbase + k * HWo);
    }

    // Phase 2: stage window into LDS as packed pairs (iters 0..3
    // unconditional -> straight-line; setup VALU below overlaps the
    // global-load latency of this phase).
    // shp[ch][row][c] = half2(img[row][c], img[row][c+1]).
#pragma unroll
    for (int i = 0; i < 5; ++i) {
        const int it = threadIdx.x + i * TPB_;
        if (i < 4 || it < NF4_) {
            const int ch  = it / (WY_ * WX4_);
            const int rem = it - ch * (WY_ * WX4_);
            const int row = rem / WX4_;
            const int c4  = rem - row * WX4_;
            const float* src = imgb + ch * (H_ * W_) + (wylo + row) * W_ + wxlo;
            const float4 v = ((const float4*)src)[c4];
            int gx = 4 * c4 + 4;                       // next element
            gx = (wxlo + gx > W_ - 1) ? (W_ - 1 - wxlo) : gx;  // clamp (unread pair)
            const float nx = src[gx];
            __half2 p0 = __float22half2_rn(make_float2(v.x, v.y));
            __half2 p1 = __float22half2_rn(make_float2(v.y, v.z));
            __half2 p2 = __float22half2_rn(make_float2(v.z, v.w));
            __half2 p3 = __float22half2_rn(make_float2(v.w, nx));
            __half2* dst = shp + ch * WCH_ + row * WX_ + 4 * c4;
            dst[0] = p0; dst[1] = p1; dst[2] = p2; dst[3] = p3;
        }
    }

    // (ox+0.5)/WO*W - 0.5 == 2*ox + 0.5  (exact in fp32; W/WO = 2)
    const float cx = 2.0f * (float)ox + 0.5f;
    const float cy = 2.0f * (float)oy + 0.5f;

    // Phase A (pre-barrier): per-tap setup from stream values only.
    int  idx[K2_];
    h2v  axt[K2_], axb[K2_];
    unsigned miss = 0u;
#pragma unroll
    for (int k = 0; k < K2_; ++k) {
        const float px = cx + (float)(k % KS_) + oh[k] * unit;
        const float py = cy + (float)(k / KS_) + ov[k] * unit;
        const float fx = floorf(px);
        const float fy = floorf(py);
        const float a  = px - fx;
        const float bt = py - fy;
        const int x0 = (int)fx - 1;
        const int y0 = (int)fy - 1;

        const bool inwin = (x0 >= wxlo) & (x0 <= wxlo + WX_ - 2)
                         & (y0 >= wylo) & (y0 <= wylo + WY_ - 2);
        miss |= (inwin ? 0u : 1u) << k;

        const float wt = wk[k] * (1.0f - bt);
        const float wb = wk[k] * bt;
        const float ax0 = 1.0f - a;
        axt[k] = __builtin_amdgcn_cvt_pkrtz(wt * ax0, wt * a);
        axb[k] = __builtin_amdgcn_cvt_pkrtz(wb * ax0, wb * a);
        idx[k] = (y0 - wylo) * WX_ + (x0 - wxlo);
    }

    __syncthreads();

    float acc0 = 0.0f, acc1 = 0.0f, acc2 = 0.0f;

    // Phase B: LDS consume (fast path) + cold exact fallback.
#pragma unroll
    for (int k = 0; k < K2_; ++k) {
        if (!(miss & (1u << k))) {
            const int i_t = idx[k];
            const h2v at = axt[k], ab = axb[k];
            {
                const __half2* hp = shp;
                acc0 = __builtin_amdgcn_fdot2(ldh2(hp + i_t),       at, acc0, false);
                acc0 = __builtin_amdgcn_fdot2(ldh2(hp + i_t + WX_), ab, acc0, false);
            }
            {
                const __half2* hp = shp + WCH_;
                acc1 = __builtin_amdgcn_fdot2(ldh2(hp + i_t),       at, acc1, false);
                acc1 = __builtin_amdgcn_fdot2(ldh2(hp + i_t + WX_), ab, acc1, false);
            }
            {
                const __half2* hp = shp + 2 * WCH_;
                acc2 = __builtin_amdgcn_fdot2(ldh2(hp + i_t),       at, acc2, false);
                acc2 = __builtin_amdgcn_fdot2(ldh2(hp + i_t + WX_), ab, acc2, false);
            }
        } else {
            // cold exact path: reload stream values (global, rare),
            // full reference clip+reflect in fp32.
            const float wkf = kern[kbase + k * HWo];
            const float ohf = offh[kbase + k * HWo];
            const float ovf = offv[kbase + k * HWo];
            const float px = cx + (float)(k % KS_) + ohf * unit;
            const float py = cy + (float)(k / KS_) + ovf * unit;
            const float fx = floorf(px);
            const float fy = floorf(py);
            const float a  = px - fx;
            const float bt = py - fy;

            int xL = (int)fx; xL = xL < 0 ? 0 : (xL > WP_ - 1 ? WP_ - 1 : xL);
            int xR = xL + 1;  xR = xR > WP_ - 1 ? WP_ - 1 : xR;
            int yT = (int)fy; yT = yT < 0 ? 0 : (yT > HP_ - 1 ? HP_ - 1 : yT);
            int yB = yT + 1;  yB = yB > HP_ - 1 ? HP_ - 1 : yB;

            int xl = xL - 1; xl = (xl < 0) ? -xl : (xl >= W_ ? 2 * W_ - 2 - xl : xl);
            int xr = xR - 1; xr = (xr < 0) ? -xr : (xr >= W_ ? 2 * W_ - 2 - xr : xr);
            int yt = yT - 1; yt = (yt < 0) ? -yt : (yt >= H_ ? 2 * H_ - 2 - yt : yt);
            int yb = yB - 1; yb = (yb < 0) ? -yb : (yb >= H_ ? 2 * H_ - 2 - yb : yb);

            const int base = xl < xr ? xl : xr;
            const float ax0 = ((xl == base) ? (1.0f - a) : 0.0f)
                            + ((xr == base) ? a : 0.0f);
            const float ax1 = 1.0f - ax0;
            const float wt = wkf * (1.0f - bt);
            const float wb = wkf * bt;

            const int r0 = yt * W_ + base;
            const int r1 = yb * W_ + base;
            {
                const float2 v = ld2(imgb + r0);
                const float2 u = ld2(imgb + r1);
                acc0 = fmaf(wt, fmaf(ax0, v.x, ax1 * v.y),
                       fmaf(wb, fmaf(ax0, u.x, ax1 * u.y), acc0));
            }
            {
                const float2 v = ld2(imgb + H_ * W_ + r0);
                const float2 u = ld2(imgb + H_ * W_ + r1);
                acc1 = fmaf(wt, fmaf(ax0, v.x, ax1 * v.y),
                       fmaf(wb, fmaf(ax0, u.x, ax1 * u.y), acc1));
            }
            {
                const float2 v = ld2(imgb + 2 * H_ * W_ + r0);
                const float2 u = ld2(imgb + 2 * H_ * W_ + r1);
                acc2 = fmaf(wt, fmaf(ax0, v.x, ax1 * v.y),
                       fmaf(wb, fmaf(ax0, u.x, ax1 * u.y), acc2));
            }
        }
    }

    const int obase = b * (C_ * HWo) + oy * WO_ + ox;
    out[obase]           = acc0;
    out[obase + HWo]     = acc1;
    out[obase + 2 * HWo] = acc2;
}

extern "C" void kernel_launch(void* const* d_in, const int* in_sizes, int n_in,
                              void* d_out, int out_size, void* d_ws, size_t ws_size,
                              hipStream_t stream) {
    const float* img  = (const float*)d_in[0];
    const float* kern = (const float*)d_in[1];
    const float* offh = (const float*)d_in[2];
    const float* offv = (const float*)d_in[3];
    const float* unit = (const float*)d_in[4];
    float* out = (float*)d_out;

    ds_kernel<<<NBLK_, TPB_, 0, stream>>>(img, kern, offh, offv, unit, out);
}

// Round 19
// 67.940 us; speedup vs baseline: 1.3252x; 1.3252x over previous
//
#include <hip/hip_runtime.h>
#include <hip/hip_fp16.h>

// Adaptive downsampler: B=8, C=3, 1024x1024 -> 512x512, K2=9 taps,
// bilinear gather from reflect-padded (pad=1) image, weighted by kernels.
// R19 = R17 (66.0us best: fdot2 bilinear, fp16 packed-pair LDS 25x136
//       window/40960B, 512-thr/64x8 patch, 27-wide nt preload, XCD slab
//       swizzle, exact fp32 fallback, plain stores; R18's pre-barrier
//       setup REVERTED — it cost VGPR 32->60, occupancy 61->29)
//       + channel-interleaved LDS: plane A entry = 8B (c0-pair, c1-pair),
//       plane B = 4B c2-pair. Per tap: 1 ds_read2_b64 + 1 ds_read2_b32
//       = 2 insts (was 3 read2_b32) -> 18 LDS-read insts/thread (-33%),
//       same dword traffic, same LDS footprint, 8B-aligned (no risk).
constexpr int B_  = 8;
constexpr int C_  = 3;
constexpr int H_  = 1024;
constexpr int W_  = 1024;
constexpr int HO_ = 512;
constexpr int WO_ = 512;
constexpr int K2_ = 9;
constexpr int KS_ = 3;
constexpr int HP_ = H_ + 2;   // padded height (pad=1)
constexpr int WP_ = W_ + 2;   // padded width
constexpr int TPB_  = 512;
constexpr int NBLK_ = (B_ * HO_ * WO_) / TPB_;  // 4096 blocks
constexpr int NXCD_ = 8;

// LDS window: WY_ rows x WX_ pair-cols; plane A = (c0,c1) 8B entries,
// plane B = c2 4B entries. Total 25*136*12 = 40800B -> 40960 alloc.
constexpr int WY_  = 25;
constexpr int WX_  = 136;
constexpr int WX4_ = WX_ / 4;              // 34
constexpr int NU_  = WY_ * WX4_;           // 850 staging units (row, c4)

typedef __fp16 h2v __attribute__((ext_vector_type(2)));
struct A8 { h2v c0, c1; };                 // 8B plane-A entry

__device__ __forceinline__ float2 ld2(const float* p) {
    float2 r;
    __builtin_memcpy(&r, p, sizeof(float2));   // global_load_dwordx2
    return r;
}

__device__ __forceinline__ A8 ldA(const h2v* p) {
    A8 r;
    __builtin_memcpy(&r, p, 8);                // ds_read_b64 (read2_b64-paired)
    return r;
}

__device__ __forceinline__ void stA(h2v* p, h2v a, h2v b) {
    A8 v{a, b};
    __builtin_memcpy(p, &v, 8);                // ds_write_b64
}

__global__ __launch_bounds__(TPB_) void ds_kernel(
    const float* __restrict__ img,
    const float* __restrict__ kern,
    const float* __restrict__ offh,
    const float* __restrict__ offv,
    const float* __restrict__ unit_p,
    float* __restrict__ out)
{
    const int HWo = HO_ * WO_;                       // 262144
    __shared__ h2v pA[WY_ * WX_ * 2];                // 27200 B
    __shared__ h2v pB[WY_ * WX_];                    // 13600 B

    // XCD swizzle: block i runs on XCD i%8; contiguous 512-block slab
    // per XCD = one batch, oy-ordered -> image window L2-resident.
    const int wg  = blockIdx.x;
    const int nid = (wg & (NXCD_ - 1)) * (NBLK_ / NXCD_) + (wg >> 3);

    // 2D patch decode: nid = b*512 + oyt*8 + oxt
    const int b   = nid >> 9;
    const int q   = nid & 511;
    const int oyt = q >> 3;             // 0..63: 8-row oy group
    const int oxt = q & 7;              // 0..7:  64-px ox chunk
    const int wv  = threadIdx.x >> 6;   // 0..7
    const int ln  = threadIdx.x & 63;
    const int oy  = oyt * 8 + wv;
    const int ox  = oxt * 64 + ln;

    const float unit = unit_p[0];
    const float* imgb = img + (size_t)b * (C_ * H_ * W_);
    const int kbase = b * (K2_ * HWo) + oy * WO_ + ox;   // < 2^25

    // Window origin (orig-image coords), x 4-aligned for float4 staging.
    int wxlo = 128 * oxt - 4;
    wxlo = wxlo < 0 ? 0 : (wxlo > W_ - WX_ ? W_ - WX_ : wxlo);   // 0..888, %4==0
    int wylo = 16 * oyt - 4;
    wylo = wylo < 0 ? 0 : (wylo > H_ - WY_ ? H_ - WY_ : wylo);   // 0..999

    // Phase 1: all 27 stream loads in flight (read-once -> nontemporal).
    float wk[K2_], oh[K2_], ov[K2_];
#pragma unroll
    for (int k = 0; k < K2_; ++k) {
        wk[k] = __builtin_nontemporal_load(kern + kbase + k * HWo);
        oh[k] = __builtin_nontemporal_load(offh + kbase + k * HWo);
        ov[k] = __builtin_nontemporal_load(offv + kbase + k * HWo);
    }

    // Phase 2: stage window into LDS. Unit = (row, 4 cols), all 3 channels:
    // pA[2e..2e+1] = (c0 pair, c1 pair); pB[e] = c2 pair.
#pragma unroll
    for (int i = 0; i < 2; ++i) {
        const int it = threadIdx.x + i * TPB_;
        if (it < NU_) {
            const int row = it / WX4_;
            const int c4  = it - row * WX4_;
            const float* s0 = imgb + (wylo + row) * W_ + wxlo;
            const float* s1 = s0 + H_ * W_;
            const float* s2 = s0 + 2 * H_ * W_;
            const float4 v0 = ((const float4*)s0)[c4];
            const float4 v1 = ((const float4*)s1)[c4];
            const float4 v2 = ((const float4*)s2)[c4];
            int gx = 4 * c4 + 4;                               // next element
            gx = (wxlo + gx > W_ - 1) ? (W_ - 1 - wxlo) : gx;  // clamp
            const float n0 = s0[gx], n1 = s1[gx], n2 = s2[gx];

            const int e0 = row * WX_ + 4 * c4;
            stA(pA + 2 * (e0 + 0), __builtin_amdgcn_cvt_pkrtz(v0.x, v0.y),
                                   __builtin_amdgcn_cvt_pkrtz(v1.x, v1.y));
            stA(pA + 2 * (e0 + 1), __builtin_amdgcn_cvt_pkrtz(v0.y, v0.z),
                                   __builtin_amdgcn_cvt_pkrtz(v1.y, v1.z));
            stA(pA + 2 * (e0 + 2), __builtin_amdgcn_cvt_pkrtz(v0.z, v0.w),
                                   __builtin_amdgcn_cvt_pkrtz(v1.z, v1.w));
            stA(pA + 2 * (e0 + 3), __builtin_amdgcn_cvt_pkrtz(v0.w, n0),
                                   __builtin_amdgcn_cvt_pkrtz(v1.w, n1));
            pB[e0 + 0] = __builtin_amdgcn_cvt_pkrtz(v2.x, v2.y);
            pB[e0 + 1] = __builtin_amdgcn_cvt_pkrtz(v2.y, v2.z);
            pB[e0 + 2] = __builtin_amdgcn_cvt_pkrtz(v2.z, v2.w);
            pB[e0 + 3] = __builtin_amdgcn_cvt_pkrtz(v2.w, n2);
        }
    }
    __syncthreads();

    // (ox+0.5)/WO*W - 0.5 == 2*ox + 0.5  (exact in fp32; W/WO = 2)
    const float cx = 2.0f * (float)ox + 0.5f;
    const float cy = 2.0f * (float)oy + 0.5f;

    float acc0 = 0.0f, acc1 = 0.0f, acc2 = 0.0f;

    // Phase 3: taps, fully unrolled; fdot2 LDS fast path + exact fallback.
#pragma unroll
    for (int k = 0; k < K2_; ++k) {
        const float px = cx + (float)(k % KS_) + oh[k] * unit;
        const float py = cy + (float)(k / KS_) + ov[k] * unit;

        const float fx = floorf(px);
        const float fy = floorf(py);
        const float a  = px - fx;   // alpha
        const float bt = py - fy;   // beta

        // raw corner (orig coords); if in window, clip is inactive and
        // reflect is identity (window subset of [0,W-1]x[0,H-1]).
        const int x0 = (int)fx - 1;
        const int y0 = (int)fy - 1;

        const float wt = wk[k] * (1.0f - bt);
        const float wb = wk[k] * bt;

        const bool inwin = (x0 >= wxlo) & (x0 <= wxlo + WX_ - 2)
                         & (y0 >= wylo) & (y0 <= wylo + WY_ - 2);

        if (inwin) {
            const float ax0 = 1.0f - a;
            // fold row weights into packed half2: one fdot2 per row per ch
            const h2v at = __builtin_amdgcn_cvt_pkrtz(wt * ax0, wt * a);
            const h2v ab = __builtin_amdgcn_cvt_pkrtz(wb * ax0, wb * a);
            const int i_t = (y0 - wylo) * WX_ + (x0 - wxlo);

            const A8 t = ldA(pA + 2 * i_t);            // c0t, c1t
            const A8 u = ldA(pA + 2 * (i_t + WX_));    // c0b, c1b
            const h2v c2t = pB[i_t];
            const h2v c2b = pB[i_t + WX_];

            acc0 = __builtin_amdgcn_fdot2(t.c0, at, acc0, false);
            acc0 = __builtin_amdgcn_fdot2(u.c0, ab, acc0, false);
            acc1 = __builtin_amdgcn_fdot2(t.c1, at, acc1, false);
            acc1 = __builtin_amdgcn_fdot2(u.c1, ab, acc1, false);
            acc2 = __builtin_amdgcn_fdot2(c2t,  at, acc2, false);
            acc2 = __builtin_amdgcn_fdot2(c2b,  ab, acc2, false);
        } else {
            // exact reference semantics: clip in padded coords + reflect,
            // fp32 global reads (precision preserved for outliers).
            int xL = (int)fx; xL = xL < 0 ? 0 : (xL > WP_ - 1 ? WP_ - 1 : xL);
            int xR = xL + 1;  xR = xR > WP_ - 1 ? WP_ - 1 : xR;
            int yT = (int)fy; yT = yT < 0 ? 0 : (yT > HP_ - 1 ? HP_ - 1 : yT);
            int yB = yT + 1;  yB = yB > HP_ - 1 ? HP_ - 1 : yB;

            int xl = xL - 1; xl = (xl < 0) ? -xl : (xl >= W_ ? 2 * W_ - 2 - xl : xl);
            int xr = xR - 1; xr = (xr < 0) ? -xr : (xr >= W_ ? 2 * W_ - 2 - xr : xr);
            int yt = yT - 1; yt = (yt < 0) ? -yt : (yt >= H_ ? 2 * H_ - 2 - yt : yt);
            int yb = yB - 1; yb = (yb < 0) ? -yb : (yb >= H_ ? 2 * H_ - 2 - yb : yb);

            const int base = xl < xr ? xl : xr;
            const float ax0 = ((xl == base) ? (1.0f - a) : 0.0f)
                            + ((xr == base) ? a : 0.0f);
            const float ax1 = 1.0f - ax0;

            const int r0 = yt * W_ + base;
            const int r1 = yb * W_ + base;
            {
                const float2 v = ld2(imgb + r0);
                const float2 u = ld2(imgb + r1);
                acc0 = fmaf(wt, fmaf(ax0, v.x, ax1 * v.y),
                       fmaf(wb, fmaf(ax0, u.x, ax1 * u.y), acc0));
            }
            {
                const float2 v = ld2(imgb + H_ * W_ + r0);
                const float2 u = ld2(imgb + H_ * W_ + r1);
                acc1 = fmaf(wt, fmaf(ax0, v.x, ax1 * v.y),
                       fmaf(wb, fmaf(ax0, u.x, ax1 * u.y), acc1));
            }
            {
                const float2 v = ld2(imgb + 2 * H_ * W_ + r0);
                const float2 u = ld2(imgb + 2 * H_ * W_ + r1);
                acc2 = fmaf(wt, fmaf(ax0, v.x, ax1 * v.y),
                       fmaf(wb, fmaf(ax0, u.x, ax1 * u.y), acc2));
            }
        }
    }

    const int obase = b * (C_ * HWo) + oy * WO_ + ox;
    out[obase]           = acc0;
    out[obase + HWo]     = acc1;
    out[obase + 2 * HWo] = acc2;
}

extern "C" void kernel_launch(void* const* d_in, const int* in_sizes, int n_in,
                              void* d_out, int out_size, void* d_ws, size_t ws_size,
                              hipStream_t stream) {
    const float* img  = (const float*)d_in[0];
    const float* kern = (const float*)d_in[1];
    const float* offh = (const float*)d_in[2];
    const float* offv = (const float*)d_in[3];
    const float* unit = (const float*)d_in[4];
    float* out = (float*)d_out;

    ds_kernel<<<NBLK_, TPB_, 0, stream>>>(img, kern, offh, offv, unit, out);
}